// Round 3
// baseline (310.163 us; speedup 1.0000x reference)
//
#include <hip/hip_runtime.h>
#include <stdint.h>

// ---------------------------------------------------------------------------
// MultiHeadAttention  B=2 S=2048 D=1024 H=16 HD=64   (fp32 in/out, bf16 MFMA)
// Pipeline: convert->bf16 (1 launch), fused QKV GEMM, flash attention
// (fixed-max softmax, register-prefetch K/V staging), output GEMM.
// ---------------------------------------------------------------------------

typedef __bf16 bf16x8 __attribute__((ext_vector_type(8)));
typedef float  f32x4  __attribute__((ext_vector_type(4)));

#define LOG2E 1.44269504088896f
#define FIXED_MAX_BITS 14.4269504088896f   /* 10 nats * log2(e) */

__device__ __forceinline__ unsigned short f2bf(float f) {
    union { float f; unsigned u; } v; v.f = f;
    unsigned r = v.u + 0x7FFFu + ((v.u >> 16) & 1u);   // round-to-nearest-even
    return (unsigned short)(r >> 16);
}

__device__ __forceinline__ float exp2_fast(float x) {
#if __has_builtin(__builtin_amdgcn_exp2f)
    return __builtin_amdgcn_exp2f(x);
#else
    return __expf(x * 0.69314718056f);
#endif
}

// async global->LDS, 16B per lane; lds dest = wave-uniform base + lane*16
__device__ __forceinline__ void glds16(const void* g, void* l) {
    __builtin_amdgcn_global_load_lds(
        (__attribute__((address_space(1))) void*)(g),
        (__attribute__((address_space(3))) void*)(l),
        16, 0, 0);
}

// ---------------------------------------------------------------------------
// fp32 -> bf16 convert: x (1M float4) + 4 weights (256K float4 each), 1 launch
// ---------------------------------------------------------------------------
__global__ __launch_bounds__(256) void cvt_all(
    const float* __restrict__ x,  const float* __restrict__ Wq,
    const float* __restrict__ Wk, const float* __restrict__ Wv,
    const float* __restrict__ Wo,
    unsigned short* __restrict__ xb,  unsigned short* __restrict__ Wqb,
    unsigned short* __restrict__ Wkb, unsigned short* __restrict__ Wvb,
    unsigned short* __restrict__ Wob)
{
    const int stride = gridDim.x * blockDim.x;
    for (int i = blockIdx.x * blockDim.x + threadIdx.x; i < 2097152; i += stride) {
        const float* src; unsigned short* dst; int j;
        if (i < 1048576) { src = x; dst = xb; j = i; }
        else {
            int t = (i - 1048576) >> 18; j = (i - 1048576) & 262143;
            src = (t == 0) ? Wq : (t == 1) ? Wk : (t == 2) ? Wv : Wo;
            dst = (t == 0) ? Wqb : (t == 1) ? Wkb : (t == 2) ? Wvb : Wob;
        }
        float4 v = ((const float4*)src)[j];
        ushort4 o;
        o.x = f2bf(v.x); o.y = f2bf(v.y); o.z = f2bf(v.z); o.w = f2bf(v.w);
        ((ushort4*)dst)[j] = o;
    }
}

// ---------------------------------------------------------------------------
// GEMM  C[m][n] = sum_k A[m][k] * W[n][k]  (+bias)   A:[Mx1024] W:[Nx1024] bf16
// BMx128 tile, BK=64, 256 thr = 4 waves, 16x16x32 MFMA.
// MODE 0 (BM=128): N=3072 (Q|K|V); Q scaled by 0.125*log2e, K as [bh][s][hd],
//                  V transposed [bh][hd][s].
// MODE 1 (BM=64):  N=1024, fp32 out (+bias), 512 blocks for occupancy.
// LDS rows of 8 16B-chunks, chunk XOR-swizzled by (row&7) -> conflict-free.
// ---------------------------------------------------------------------------
template <int MODE>
__global__ __launch_bounds__(256) void gemm_bt(
    const unsigned short* __restrict__ A,
    const unsigned short* __restrict__ W0,
    const unsigned short* __restrict__ W1,
    const unsigned short* __restrict__ W2,
    const float* __restrict__ b0,
    const float* __restrict__ b1,
    const float* __restrict__ b2,
    unsigned short* __restrict__ outQ,
    unsigned short* __restrict__ outK,
    unsigned short* __restrict__ outV,
    float* __restrict__ outF)
{
    constexpr int BM = (MODE == 0) ? 128 : 64;
    constexpr int FM = BM / 32;          // A-frags per wave (4 or 2)
    constexpr int RA = BM / 32;          // staging rounds for A (4 or 2)

    __shared__ __attribute__((aligned(16))) unsigned short As[BM * 64];
    __shared__ __attribute__((aligned(16))) unsigned short Bs[128 * 64];

    const int tid  = threadIdx.x;
    const int lane = tid & 63;
    const int wid  = tid >> 6;
    const int quad = lane >> 4;
    const int l16  = lane & 15;

    const int m0 = blockIdx.x * BM;

    const unsigned short* W;
    const float* bias;
    int proj, n0;
    if (MODE == 0) {
        proj = blockIdx.y >> 3;              // 0=Q 1=K 2=V
        n0   = (blockIdx.y & 7) * 128;
        W    = (proj == 0) ? W0 : (proj == 1) ? W1 : W2;
        bias = (proj == 0) ? b0 : (proj == 1) ? b1 : b2;
    } else {
        proj = 0;
        n0   = blockIdx.y * 128;
        W    = W0;
        bias = b0;
    }

    const int wm = (wid >> 1) * (BM / 2);
    const int wn = (wid & 1) * 64;

    f32x4 acc[FM][4];
#pragma unroll
    for (int i = 0; i < FM; ++i)
#pragma unroll
        for (int j = 0; j < 4; ++j)
            acc[i][j] = (f32x4){0.f, 0.f, 0.f, 0.f};

    char* AsB  = (char*)As;
    char* BsB  = (char*)Bs;
    char* ldsA = AsB + wid * 1024;   // wave-uniform dest base
    char* ldsB = BsB + wid * 1024;

    for (int k0 = 0; k0 < 1024; k0 += 64) {
#pragma unroll
        for (int q = 0; q < RA; ++q) {
            int i   = q * 256 + tid;
            int row = i >> 3;
            int sc  = (i & 7) ^ (row & 7);
            glds16(A + (size_t)(m0 + row) * 1024 + k0 + sc * 8, ldsA + q * 4096);
        }
#pragma unroll
        for (int q = 0; q < 4; ++q) {
            int i   = q * 256 + tid;
            int row = i >> 3;
            int sc  = (i & 7) ^ (row & 7);
            glds16(W + (size_t)(n0 + row) * 1024 + k0 + sc * 8, ldsB + q * 4096);
        }
        __syncthreads();

#pragma unroll
        for (int kh = 0; kh < 2; ++kh) {
            bf16x8 af[FM], bfr[4];
#pragma unroll
            for (int t = 0; t < FM; ++t) {
                int r = wm + t * 16 + l16;
                int c = (kh * 4 + quad) ^ (r & 7);
                af[t] = *(const bf16x8*)(AsB + r * 128 + c * 16);
            }
#pragma unroll
            for (int t = 0; t < 4; ++t) {
                int r = wn + t * 16 + l16;
                int c = (kh * 4 + quad) ^ (r & 7);
                bfr[t] = *(const bf16x8*)(BsB + r * 128 + c * 16);
            }
#pragma unroll
            for (int i = 0; i < FM; ++i)
#pragma unroll
                for (int j = 0; j < 4; ++j)
                    acc[i][j] = __builtin_amdgcn_mfma_f32_16x16x32_bf16(
                        af[i], bfr[j], acc[i][j], 0, 0, 0);
        }
        __syncthreads();
    }

    // epilogue; C/D layout: col = lane&15, row = quad*4 + reg
#pragma unroll
    for (int i = 0; i < FM; ++i) {
        const int mrow0 = m0 + wm + i * 16 + quad * 4;
#pragma unroll
        for (int j = 0; j < 4; ++j) {
            const int n  = n0 + wn + j * 16 + l16;
            const float bb = bias[n];
            if (MODE == 1) {
#pragma unroll
                for (int r = 0; r < 4; ++r)
                    outF[(size_t)(mrow0 + r) * 1024 + n] = acc[i][j][r] + bb;
            } else {
                const int h = n >> 6, hd = n & 63;
                if (proj == 2) {
                    // V transposed: [bh][hd][s]; 4 regs = 4 consecutive s
                    const int b = mrow0 >> 11, s = mrow0 & 2047;
                    ushort4 pk;
                    pk.x = f2bf(acc[i][j][0] + bb);
                    pk.y = f2bf(acc[i][j][1] + bb);
                    pk.z = f2bf(acc[i][j][2] + bb);
                    pk.w = f2bf(acc[i][j][3] + bb);
                    *(ushort4*)(outV + ((size_t)((b * 16 + h) * 64 + hd)) * 2048 + s) = pk;
                } else {
                    unsigned short* dst = (proj == 0) ? outQ : outK;
                    // Q pre-scaled by 1/sqrt(64) * log2(e) so QK^T is bits-of-exp2
                    const float scl = (proj == 0) ? (0.125f * LOG2E) : 1.0f;
#pragma unroll
                    for (int r = 0; r < 4; ++r) {
                        const int m = mrow0 + r;
                        const int b = m >> 11, s = m & 2047;
                        dst[((size_t)((b * 16 + h) * 2048 + s)) * 64 + hd] =
                            f2bf((acc[i][j][r] + bb) * scl);
                    }
                }
            }
        }
    }
}

// ---------------------------------------------------------------------------
// Flash attention, fixed-max softmax. 1 block = (bh, 64 Q rows), 4 waves.
// K/V staged global->VGPR->LDS (NOT global_load_lds): plain register loads
// carry no shared-memory hazard, so __syncthreads() does not drain vmcnt.
// The vmcnt wait lands on the ds_write at the top of the NEXT iteration —
// an entire compute phase (exp2 + P roundtrip + 32 MFMAs) hides the load.
// Loop: store regs->LDS; barrier; prefetch next->regs; compute; barrier.
// p = exp2(QK^T*log2e - 10*log2e): -M is the MFMA acc init, log2e baked in Q.
// ---------------------------------------------------------------------------
__global__ __launch_bounds__(256, 4) void attn_kernel(
    const unsigned short* __restrict__ Qb,   // [32][2048][64]
    const unsigned short* __restrict__ Kb,   // [32][2048][64]
    const unsigned short* __restrict__ Vtb,  // [32][64][2048]
    unsigned short* __restrict__ Ob)         // [4096][1024]
{
    __shared__ __attribute__((aligned(16))) unsigned short Ks[128 * 64];    // 16 KB
    __shared__ __attribute__((aligned(16))) unsigned short Vs[2 * 64 * 64]; // 16 KB
    __shared__ __attribute__((aligned(16))) unsigned short Ps[4][16 * 64];  //  8 KB

    const int tid  = threadIdx.x;
    const int lane = tid & 63;
    const int wid  = tid >> 6;
    const int quad = lane >> 4;
    const int l16  = lane & 15;

    const int q0 = blockIdx.x * 64;
    const int hb = blockIdx.y;              // b*16 + h
    const int bq = hb >> 4, hh = hb & 15;

    const unsigned short* Qh  = Qb  + (size_t)hb * 2048 * 64;
    const unsigned short* Kh  = Kb  + (size_t)hb * 2048 * 64;
    const unsigned short* Vth = Vtb + (size_t)hb * 64 * 2048;

    // Q A-frags: A[m=lane&15][k=quad*8+j], two k-halves
    const int mq = q0 + wid * 16 + l16;
    const unsigned short* qp = Qh + (size_t)mq * 64 + quad * 8;
    const bf16x8 aq0 = *(const bf16x8*)(qp);
    const bf16x8 aq1 = *(const bf16x8*)(qp + 32);

    f32x4 o[4];
#pragma unroll
    for (int t = 0; t < 4; ++t) o[t] = (f32x4){0.f, 0.f, 0.f, 0.f};
    float lsum[4] = {0.f, 0.f, 0.f, 0.f};

    char* KsB = (char*)Ks;
    unsigned short* Pw = Ps[wid];           // per-wave private -> no barrier

    // per-thread staging addresses (chunk-invariant parts precomputed)
    // K rounds q=0..3: row=(q*256+tid)>>3, sc=((q*256+tid)&7)^(row&7)
    // V rounds (sub,q): row=(q*256+tid)>>3, same sc
    int krow[4], ksc[4];
#pragma unroll
    for (int q = 0; q < 4; ++q) {
        int i = q * 256 + tid;
        krow[q] = i >> 3;
        ksc[q]  = (i & 7) ^ (krow[q] & 7);
    }

    float4 kv[8];   // 4 K rounds + 4 V rounds (sub-major)

    // prefetch chunk 0
#pragma unroll
    for (int q = 0; q < 4; ++q)
        kv[q] = *(const float4*)(Kh + (size_t)krow[q] * 64 + ksc[q] * 8);
#pragma unroll
    for (int sub = 0; sub < 2; ++sub)
#pragma unroll
        for (int q = 0; q < 2; ++q)
            kv[4 + sub * 2 + q] = *(const float4*)
                (Vth + (size_t)krow[q] * 2048 + sub * 64 + ksc[q] * 8);

    for (int kc = 0; kc < 2048; kc += 128) {
        // commit prefetched regs to LDS (vmcnt wait happens HERE, post-compute)
#pragma unroll
        for (int q = 0; q < 4; ++q)
            *(float4*)(KsB + wid * 1024 + q * 4096 + lane * 16) = kv[q];
#pragma unroll
        for (int sub = 0; sub < 2; ++sub)
#pragma unroll
            for (int q = 0; q < 2; ++q)
                *(float4*)((char*)Vs + sub * 8192 + wid * 1024 + q * 4096 + lane * 16)
                    = kv[4 + sub * 2 + q];
        __syncthreads();

        // prefetch next chunk into regs (no LDS hazard -> no barrier drain)
        if (kc + 128 < 2048) {
            const int kn = kc + 128;
#pragma unroll
            for (int q = 0; q < 4; ++q)
                kv[q] = *(const float4*)
                    (Kh + (size_t)(kn + krow[q]) * 64 + ksc[q] * 8);
#pragma unroll
            for (int sub = 0; sub < 2; ++sub)
#pragma unroll
                for (int q = 0; q < 2; ++q)
                    kv[4 + sub * 2 + q] = *(const float4*)
                        (Vth + (size_t)krow[q] * 2048 + kn + sub * 64 + ksc[q] * 8);
        }

#pragma unroll
        for (int ss = 0; ss < 2; ++ss) {
            char* VsB = (char*)Vs + ss * 8192;

            // scores: 16x64 per wave; acc init = -M -> p = exp2(acc) directly
            f32x4 p[4];
#pragma unroll
            for (int nt = 0; nt < 4; ++nt) {
                const int srow = ss * 64 + nt * 16 + l16;
                const int c0 = quad ^ (srow & 7);
                const int c1 = (4 + quad) ^ (srow & 7);
                bf16x8 k0 = *(const bf16x8*)(KsB + srow * 128 + c0 * 16);
                bf16x8 k1 = *(const bf16x8*)(KsB + srow * 128 + c1 * 16);
                f32x4 t = (f32x4){-FIXED_MAX_BITS, -FIXED_MAX_BITS,
                                  -FIXED_MAX_BITS, -FIXED_MAX_BITS};
                t = __builtin_amdgcn_mfma_f32_16x16x32_bf16(aq0, k0, t, 0, 0, 0);
                t = __builtin_amdgcn_mfma_f32_16x16x32_bf16(aq1, k1, t, 0, 0, 0);
                p[nt] = t;
            }
#pragma unroll
            for (int nt = 0; nt < 4; ++nt)
#pragma unroll
                for (int r = 0; r < 4; ++r)
                    p[nt][r] = exp2_fast(p[nt][r]);
#pragma unroll
            for (int r = 0; r < 4; ++r)
                lsum[r] += (p[0][r] + p[1][r]) + (p[2][r] + p[3][r]);

            // P (C-layout) -> LDS bf16 (swizzled) -> reload in A-layout
#pragma unroll
            for (int nt = 0; nt < 4; ++nt) {
                const int col = nt * 16 + l16;
                const int cch = col >> 3, cin = col & 7;
#pragma unroll
                for (int r = 0; r < 4; ++r) {
                    const int m = quad * 4 + r;
                    Pw[m * 64 + ((cch ^ (m & 7)) << 3) + cin] = f2bf(p[nt][r]);
                }
            }
            bf16x8 ap0, ap1;
            {
                const int m  = l16;
                const int c0 = quad ^ (m & 7);
                const int c1 = (4 + quad) ^ (m & 7);
                ap0 = *(const bf16x8*)((char*)Pw + m * 128 + c0 * 16);
                ap1 = *(const bf16x8*)((char*)Pw + m * 128 + c1 * 16);
            }

            // o += P * V   (B[k][n] = V[s=k][hd=n] = Vt[n][k], k-contiguous)
#pragma unroll
            for (int ot = 0; ot < 4; ++ot) {
                const int n  = ot * 16 + l16;
                const int c0 = quad ^ (n & 7);
                const int c1 = (4 + quad) ^ (n & 7);
                bf16x8 v0 = *(const bf16x8*)(VsB + n * 128 + c0 * 16);
                bf16x8 v1 = *(const bf16x8*)(VsB + n * 128 + c1 * 16);
                o[ot] = __builtin_amdgcn_mfma_f32_16x16x32_bf16(ap0, v0, o[ot], 0, 0, 0);
                o[ot] = __builtin_amdgcn_mfma_f32_16x16x32_bf16(ap1, v1, o[ot], 0, 0, 0);
            }
        }
        __syncthreads();
    }

    // deferred l reduction: row (quad*4+r) is spread over the 16 lanes of quad
    float rl[4];
#pragma unroll
    for (int r = 0; r < 4; ++r) {
        float s = lsum[r];
        s += __shfl_xor(s, 1);
        s += __shfl_xor(s, 2);
        s += __shfl_xor(s, 4);
        s += __shfl_xor(s, 8);
        rl[r] = 1.0f / s;
    }
#pragma unroll
    for (int ot = 0; ot < 4; ++ot) {
        const int hd = ot * 16 + l16;
#pragma unroll
        for (int r = 0; r < 4; ++r) {
            const int m = q0 + wid * 16 + quad * 4 + r;
            Ob[(size_t)(bq * 2048 + m) * 1024 + hh * 64 + hd] = f2bf(o[ot][r] * rl[r]);
        }
    }
}

// ---------------------------------------------------------------------------
// launch
// ---------------------------------------------------------------------------
extern "C" void kernel_launch(void* const* d_in, const int* in_sizes, int n_in,
                              void* d_out, int out_size, void* d_ws, size_t ws_size,
                              hipStream_t stream) {
    (void)in_sizes; (void)n_in; (void)out_size; (void)ws_size;

    const float* x  = (const float*)d_in[0];
    const float* Wq = (const float*)d_in[1];
    const float* bq = (const float*)d_in[2];
    const float* Wk = (const float*)d_in[3];
    const float* bk = (const float*)d_in[4];
    const float* Wv = (const float*)d_in[5];
    const float* bv = (const float*)d_in[6];
    const float* Wo = (const float*)d_in[7];
    const float* bo = (const float*)d_in[8];

    char* ws = (char*)d_ws;
    const size_t MB = 1024 * 1024;
    unsigned short* xb    = (unsigned short*)(ws + 0);        //  8 MB [4096][1024]
    unsigned short* Wqb   = (unsigned short*)(ws + 8  * MB);  //  2 MB
    unsigned short* Wkb   = (unsigned short*)(ws + 10 * MB);
    unsigned short* Wvb   = (unsigned short*)(ws + 12 * MB);
    unsigned short* Wob   = (unsigned short*)(ws + 14 * MB);
    unsigned short* Qb    = (unsigned short*)(ws + 16 * MB);  //  8 MB [32][2048][64]
    unsigned short* Kb    = (unsigned short*)(ws + 24 * MB);  //  8 MB
    unsigned short* Vtb   = (unsigned short*)(ws + 32 * MB);  //  8 MB [32][64][2048]
    unsigned short* attnb = (unsigned short*)(ws + 40 * MB);  //  8 MB [4096][1024]

    cvt_all<<<dim3(1024), dim3(256), 0, stream>>>(
        x, Wq, Wk, Wv, Wo, xb, Wqb, Wkb, Wvb, Wob);

    gemm_bt<0><<<dim3(32, 24), dim3(256), 0, stream>>>(
        xb, Wqb, Wkb, Wvb, bq, bk, bv, Qb, Kb, Vtb, nullptr);

    attn_kernel<<<dim3(32, 32), dim3(256), 0, stream>>>(Qb, Kb, Vtb, attnb);

    gemm_bt<1><<<dim3(64, 8), dim3(256), 0, stream>>>(
        attnb, Wob, nullptr, nullptr, bo, nullptr, nullptr,
        nullptr, nullptr, nullptr, (float*)d_out);
}

// Round 4
// 208.571 us; speedup vs baseline: 1.4871x; 1.4871x over previous
//
#include <hip/hip_runtime.h>
#include <stdint.h>

// ---------------------------------------------------------------------------
// MultiHeadAttention  B=2 S=2048 D=1024 H=16 HD=64   (fp32 in/out, bf16 MFMA)
// Pipeline: convert->bf16, fused QKV GEMM, flash attention (S^T formulation,
// no P LDS round-trip), output GEMM.
// ---------------------------------------------------------------------------

typedef __bf16 bf16x8 __attribute__((ext_vector_type(8)));
typedef __bf16 bf16x4 __attribute__((ext_vector_type(4)));
typedef float  f32x4  __attribute__((ext_vector_type(4)));
typedef unsigned short u16x4 __attribute__((ext_vector_type(4)));

#define LOG2E 1.44269504088896f
#define FIXED_MAX_BITS 14.4269504088896f   /* 10 nats * log2(e) */

__device__ __forceinline__ unsigned short f2bf(float f) {
    union { float f; unsigned u; } v; v.f = f;
    unsigned r = v.u + 0x7FFFu + ((v.u >> 16) & 1u);   // round-to-nearest-even
    return (unsigned short)(r >> 16);
}

__device__ __forceinline__ float exp2_fast(float x) {
#if __has_builtin(__builtin_amdgcn_exp2f)
    return __builtin_amdgcn_exp2f(x);
#else
    return __expf(x * 0.69314718056f);
#endif
}

// PV MFMA: O^T[16 hd][16 q] += V^T(A, k=quad*4+j) * P^T(B, k=quad*4+j)
// P^T B-frag register layout == S^T C-frag layout (identity mapping).
__device__ __forceinline__ f32x4 pv_mfma(bf16x4 v, bf16x4 p, f32x4 c) {
#if __has_builtin(__builtin_amdgcn_mfma_f32_16x16x16_bf16)
    return __builtin_amdgcn_mfma_f32_16x16x16_bf16(v, p, c, 0, 0, 0);
#elif __has_builtin(__builtin_amdgcn_mfma_f32_16x16x16bf16_1k)
    typedef short s16x4 __attribute__((ext_vector_type(4)));
    return __builtin_amdgcn_mfma_f32_16x16x16bf16_1k(
        __builtin_bit_cast(s16x4, v), __builtin_bit_cast(s16x4, p), c, 0, 0, 0);
#else
    // zero-pad to K=32: real k at quad*8+(0..3), zeros at quad*8+(4..7) on BOTH
    // operands -> identical sum.
    const bf16x4 z = {(__bf16)0.f, (__bf16)0.f, (__bf16)0.f, (__bf16)0.f};
    bf16x8 v8 = __builtin_shufflevector(v, z, 0, 1, 2, 3, 4, 5, 6, 7);
    bf16x8 p8 = __builtin_shufflevector(p, z, 0, 1, 2, 3, 4, 5, 6, 7);
    return __builtin_amdgcn_mfma_f32_16x16x32_bf16(v8, p8, c, 0, 0, 0);
#endif
}

// async global->LDS, 16B per lane; lds dest = wave-uniform base + lane*16
__device__ __forceinline__ void glds16(const void* g, void* l) {
    __builtin_amdgcn_global_load_lds(
        (__attribute__((address_space(1))) void*)(g),
        (__attribute__((address_space(3))) void*)(l),
        16, 0, 0);
}

// ---------------------------------------------------------------------------
// fp32 -> bf16 convert: x (1M float4) + 4 weights (256K float4 each), 1 launch
// ---------------------------------------------------------------------------
__global__ __launch_bounds__(256) void cvt_all(
    const float* __restrict__ x,  const float* __restrict__ Wq,
    const float* __restrict__ Wk, const float* __restrict__ Wv,
    const float* __restrict__ Wo,
    unsigned short* __restrict__ xb,  unsigned short* __restrict__ Wqb,
    unsigned short* __restrict__ Wkb, unsigned short* __restrict__ Wvb,
    unsigned short* __restrict__ Wob)
{
    const int stride = gridDim.x * blockDim.x;
    for (int i = blockIdx.x * blockDim.x + threadIdx.x; i < 2097152; i += stride) {
        const float* src; unsigned short* dst; int j;
        if (i < 1048576) { src = x; dst = xb; j = i; }
        else {
            int t = (i - 1048576) >> 18; j = (i - 1048576) & 262143;
            src = (t == 0) ? Wq : (t == 1) ? Wk : (t == 2) ? Wv : Wo;
            dst = (t == 0) ? Wqb : (t == 1) ? Wkb : (t == 2) ? Wvb : Wob;
        }
        float4 v = ((const float4*)src)[j];
        ushort4 o;
        o.x = f2bf(v.x); o.y = f2bf(v.y); o.z = f2bf(v.z); o.w = f2bf(v.w);
        ((ushort4*)dst)[j] = o;
    }
}

// ---------------------------------------------------------------------------
// GEMM  C[m][n] = sum_k A[m][k] * W[n][k]  (+bias)   A:[Mx1024] W:[Nx1024] bf16
// (unchanged from round 2)
// ---------------------------------------------------------------------------
template <int MODE>
__global__ __launch_bounds__(256) void gemm_bt(
    const unsigned short* __restrict__ A,
    const unsigned short* __restrict__ W0,
    const unsigned short* __restrict__ W1,
    const unsigned short* __restrict__ W2,
    const float* __restrict__ b0,
    const float* __restrict__ b1,
    const float* __restrict__ b2,
    unsigned short* __restrict__ outQ,
    unsigned short* __restrict__ outK,
    unsigned short* __restrict__ outV,
    float* __restrict__ outF)
{
    constexpr int BM = (MODE == 0) ? 128 : 64;
    constexpr int FM = BM / 32;
    constexpr int RA = BM / 32;

    __shared__ __attribute__((aligned(16))) unsigned short As[BM * 64];
    __shared__ __attribute__((aligned(16))) unsigned short Bs[128 * 64];

    const int tid  = threadIdx.x;
    const int lane = tid & 63;
    const int wid  = tid >> 6;
    const int quad = lane >> 4;
    const int l16  = lane & 15;

    const int m0 = blockIdx.x * BM;

    const unsigned short* W;
    const float* bias;
    int proj, n0;
    if (MODE == 0) {
        proj = blockIdx.y >> 3;
        n0   = (blockIdx.y & 7) * 128;
        W    = (proj == 0) ? W0 : (proj == 1) ? W1 : W2;
        bias = (proj == 0) ? b0 : (proj == 1) ? b1 : b2;
    } else {
        proj = 0;
        n0   = blockIdx.y * 128;
        W    = W0;
        bias = b0;
    }

    const int wm = (wid >> 1) * (BM / 2);
    const int wn = (wid & 1) * 64;

    f32x4 acc[FM][4];
#pragma unroll
    for (int i = 0; i < FM; ++i)
#pragma unroll
        for (int j = 0; j < 4; ++j)
            acc[i][j] = (f32x4){0.f, 0.f, 0.f, 0.f};

    char* AsB  = (char*)As;
    char* BsB  = (char*)Bs;
    char* ldsA = AsB + wid * 1024;
    char* ldsB = BsB + wid * 1024;

    for (int k0 = 0; k0 < 1024; k0 += 64) {
#pragma unroll
        for (int q = 0; q < RA; ++q) {
            int i   = q * 256 + tid;
            int row = i >> 3;
            int sc  = (i & 7) ^ (row & 7);
            glds16(A + (size_t)(m0 + row) * 1024 + k0 + sc * 8, ldsA + q * 4096);
        }
#pragma unroll
        for (int q = 0; q < 4; ++q) {
            int i   = q * 256 + tid;
            int row = i >> 3;
            int sc  = (i & 7) ^ (row & 7);
            glds16(W + (size_t)(n0 + row) * 1024 + k0 + sc * 8, ldsB + q * 4096);
        }
        __syncthreads();

#pragma unroll
        for (int kh = 0; kh < 2; ++kh) {
            bf16x8 af[FM], bfr[4];
#pragma unroll
            for (int t = 0; t < FM; ++t) {
                int r = wm + t * 16 + l16;
                int c = (kh * 4 + quad) ^ (r & 7);
                af[t] = *(const bf16x8*)(AsB + r * 128 + c * 16);
            }
#pragma unroll
            for (int t = 0; t < 4; ++t) {
                int r = wn + t * 16 + l16;
                int c = (kh * 4 + quad) ^ (r & 7);
                bfr[t] = *(const bf16x8*)(BsB + r * 128 + c * 16);
            }
#pragma unroll
            for (int i = 0; i < FM; ++i)
#pragma unroll
                for (int j = 0; j < 4; ++j)
                    acc[i][j] = __builtin_amdgcn_mfma_f32_16x16x32_bf16(
                        af[i], bfr[j], acc[i][j], 0, 0, 0);
        }
        __syncthreads();
    }

#pragma unroll
    for (int i = 0; i < FM; ++i) {
        const int mrow0 = m0 + wm + i * 16 + quad * 4;
#pragma unroll
        for (int j = 0; j < 4; ++j) {
            const int n  = n0 + wn + j * 16 + l16;
            const float bb = bias[n];
            if (MODE == 1) {
#pragma unroll
                for (int r = 0; r < 4; ++r)
                    outF[(size_t)(mrow0 + r) * 1024 + n] = acc[i][j][r] + bb;
            } else {
                const int h = n >> 6, hd = n & 63;
                if (proj == 2) {
                    const int b = mrow0 >> 11, s = mrow0 & 2047;
                    ushort4 pk;
                    pk.x = f2bf(acc[i][j][0] + bb);
                    pk.y = f2bf(acc[i][j][1] + bb);
                    pk.z = f2bf(acc[i][j][2] + bb);
                    pk.w = f2bf(acc[i][j][3] + bb);
                    *(ushort4*)(outV + ((size_t)((b * 16 + h) * 64 + hd)) * 2048 + s) = pk;
                } else {
                    unsigned short* dst = (proj == 0) ? outQ : outK;
                    const float scl = (proj == 0) ? (0.125f * LOG2E) : 1.0f;
#pragma unroll
                    for (int r = 0; r < 4; ++r) {
                        const int m = mrow0 + r;
                        const int b = m >> 11, s = m & 2047;
                        dst[((size_t)((b * 16 + h) * 2048 + s)) * 64 + hd] =
                            f2bf((acc[i][j][r] + bb) * scl);
                    }
                }
            }
        }
    }
}

// ---------------------------------------------------------------------------
// Flash attention, S^T formulation. 1 block = (bh, 128 Q rows), 4 waves x 32 Q.
// S^T = K*Q^T via 16x16x32 (A=K from LDS, B=Q from global regs): C-frag has
// row=s=quad*4+r, col=q=l16 -- identical to the 16x16x16 B-operand layout
// (k=quad*4+j, n=l16), so P^T feeds PV straight from registers: NO LDS
// round-trip. PV: O^T[hd][q] += V^T(A, 8B LDS reads) * P^T(B, registers).
// Fixed-max softmax (acc init -10*log2e; Q pre-scaled by 0.125*log2e);
// per-lane lsum partials in-loop, quad-reduce once at the end.
// ---------------------------------------------------------------------------
__global__ __launch_bounds__(256) void attn_kernel(
    const unsigned short* __restrict__ Qb,   // [32][2048][64]
    const unsigned short* __restrict__ Kb,   // [32][2048][64]
    const unsigned short* __restrict__ Vtb,  // [32][64][2048]
    unsigned short* __restrict__ Ob)         // [4096][1024]
{
    __shared__ __attribute__((aligned(16))) unsigned short Ks[128 * 64];    // 16 KB
    __shared__ __attribute__((aligned(16))) unsigned short Vs[2 * 64 * 64]; // 16 KB

    const int tid  = threadIdx.x;
    const int lane = tid & 63;
    const int wid  = tid >> 6;
    const int quad = lane >> 4;
    const int l16  = lane & 15;

    const int q0 = blockIdx.x * 128 + wid * 32;   // this wave's q base (in-seq)
    const int hb = blockIdx.y;                    // b*16 + h
    const int bq = hb >> 4, hh = hb & 15;

    const unsigned short* Qh  = Qb  + (size_t)hb * 2048 * 64;
    const unsigned short* Kh  = Kb  + (size_t)hb * 2048 * 64;
    const unsigned short* Vth = Vtb + (size_t)hb * 64 * 2048;

    // Q B-frags: B[k=d][n=q], lane n=l16 -> q, k=quad*8+j (16B contiguous)
    bf16x8 qf[2][2];
#pragma unroll
    for (int qt = 0; qt < 2; ++qt) {
        const unsigned short* qp = Qh + (size_t)(q0 + qt * 16 + l16) * 64 + quad * 8;
        qf[qt][0] = *(const bf16x8*)(qp);
        qf[qt][1] = *(const bf16x8*)(qp + 32);
    }

    f32x4 o[4][2];   // O^T accumulators: [hd-tile][q-tile]
#pragma unroll
    for (int ht = 0; ht < 4; ++ht)
#pragma unroll
        for (int qt = 0; qt < 2; ++qt)
            o[ht][qt] = (f32x4){0.f, 0.f, 0.f, 0.f};
    float lsum[2] = {0.f, 0.f};

    char* KsB = (char*)Ks;
    char* ldsK = KsB + wid * 1024;

    // K-frag LDS base offsets: row = st*16 + l16, (row&7)==(l16&7) since 16|st*16
    const int l7  = l16 & 7;
    const int kb0 = l16 * 128 + ((quad) ^ l7) * 16;
    const int kb1 = l16 * 128 + ((4 + quad) ^ l7) * 16;
    // V-frag bases (per k-step t within a 64-s subtile), 8B reads:
    // row = ht*16 + l16, chunk = (t*2 + (quad>>1)) ^ (row&7), +8B if quad odd
    int vb[4];
#pragma unroll
    for (int t = 0; t < 4; ++t)
        vb[t] = l16 * 128 + (((t * 2 + (quad >> 1)) ^ l7) * 16) + (quad & 1) * 8;

    for (int kc = 0; kc < 2048; kc += 128) {
        // stage K 128x64 (16KB, 4 rounds) + Vt 2x 64x64 (16KB, 2x2 rounds)
#pragma unroll
        for (int q = 0; q < 4; ++q) {
            int i   = q * 256 + tid;
            int row = i >> 3;
            int sc  = (i & 7) ^ (row & 7);
            glds16(Kh + (size_t)(kc + row) * 64 + sc * 8, ldsK + q * 4096);
        }
#pragma unroll
        for (int sub = 0; sub < 2; ++sub)
#pragma unroll
            for (int q = 0; q < 2; ++q) {
                int i   = q * 256 + tid;
                int row = i >> 3;
                int sc  = (i & 7) ^ (row & 7);
                glds16(Vth + (size_t)row * 2048 + kc + sub * 64 + sc * 8,
                       (char*)Vs + sub * 8192 + wid * 1024 + q * 4096);
            }
        __syncthreads();

#pragma unroll
        for (int st = 0; st < 8; ++st) {        // 8 s-tiles of 16 per chunk
            const bf16x8 k0 = *(const bf16x8*)(KsB + st * 2048 + kb0);
            const bf16x8 k1 = *(const bf16x8*)(KsB + st * 2048 + kb1);

            bf16x4 pb[2];
#pragma unroll
            for (int qt = 0; qt < 2; ++qt) {
                f32x4 s = (f32x4){-FIXED_MAX_BITS, -FIXED_MAX_BITS,
                                  -FIXED_MAX_BITS, -FIXED_MAX_BITS};
                s = __builtin_amdgcn_mfma_f32_16x16x32_bf16(k0, qf[qt][0], s, 0, 0, 0);
                s = __builtin_amdgcn_mfma_f32_16x16x32_bf16(k1, qf[qt][1], s, 0, 0, 0);
                float p0 = exp2_fast(s[0]);
                float p1 = exp2_fast(s[1]);
                float p2 = exp2_fast(s[2]);
                float p3 = exp2_fast(s[3]);
                lsum[qt] += (p0 + p1) + (p2 + p3);
                u16x4 up;
                up.x = f2bf(p0); up.y = f2bf(p1);
                up.z = f2bf(p2); up.w = f2bf(p3);
                pb[qt] = __builtin_bit_cast(bf16x4, up);
            }

            const int ssoff = (st >> 2) * 8192;
            const int tl    = st & 3;
#pragma unroll
            for (int ht = 0; ht < 4; ++ht) {
                const bf16x4 vf = *(const bf16x4*)
                    ((char*)Vs + ssoff + ht * 2048 + vb[tl]);
                o[ht][0] = pv_mfma(vf, pb[0], o[ht][0]);
                o[ht][1] = pv_mfma(vf, pb[1], o[ht][1]);
            }
        }
        __syncthreads();
    }

    // lsum: lane covers s with (s mod 16) in [quad*4, quad*4+4) -> reduce quads
    float rl[2];
#pragma unroll
    for (int qt = 0; qt < 2; ++qt) {
        float s = lsum[qt];
        s += __shfl_xor(s, 16);
        s += __shfl_xor(s, 32);
        rl[qt] = 1.0f / s;
    }

    // epilogue: O^T frag (row hd=ht*16+quad*4+r, col q=l16), scale by rl[qt]
#pragma unroll
    for (int qt = 0; qt < 2; ++qt) {
        const size_t row = (size_t)(bq * 2048 + q0 + qt * 16 + l16);
#pragma unroll
        for (int ht = 0; ht < 4; ++ht) {
            ushort4 pk;
            pk.x = f2bf(o[ht][qt][0] * rl[qt]);
            pk.y = f2bf(o[ht][qt][1] * rl[qt]);
            pk.z = f2bf(o[ht][qt][2] * rl[qt]);
            pk.w = f2bf(o[ht][qt][3] * rl[qt]);
            *(ushort4*)(Ob + row * 1024 + hh * 64 + ht * 16 + quad * 4) = pk;
        }
    }
}

// ---------------------------------------------------------------------------
// launch
// ---------------------------------------------------------------------------
extern "C" void kernel_launch(void* const* d_in, const int* in_sizes, int n_in,
                              void* d_out, int out_size, void* d_ws, size_t ws_size,
                              hipStream_t stream) {
    (void)in_sizes; (void)n_in; (void)out_size; (void)ws_size;

    const float* x  = (const float*)d_in[0];
    const float* Wq = (const float*)d_in[1];
    const float* bq = (const float*)d_in[2];
    const float* Wk = (const float*)d_in[3];
    const float* bk = (const float*)d_in[4];
    const float* Wv = (const float*)d_in[5];
    const float* bv = (const float*)d_in[6];
    const float* Wo = (const float*)d_in[7];
    const float* bo = (const float*)d_in[8];

    char* ws = (char*)d_ws;
    const size_t MB = 1024 * 1024;
    unsigned short* xb    = (unsigned short*)(ws + 0);        //  8 MB [4096][1024]
    unsigned short* Wqb   = (unsigned short*)(ws + 8  * MB);  //  2 MB
    unsigned short* Wkb   = (unsigned short*)(ws + 10 * MB);
    unsigned short* Wvb   = (unsigned short*)(ws + 12 * MB);
    unsigned short* Wob   = (unsigned short*)(ws + 14 * MB);
    unsigned short* Qb    = (unsigned short*)(ws + 16 * MB);  //  8 MB [32][2048][64]
    unsigned short* Kb    = (unsigned short*)(ws + 24 * MB);  //  8 MB
    unsigned short* Vtb   = (unsigned short*)(ws + 32 * MB);  //  8 MB [32][64][2048]
    unsigned short* attnb = (unsigned short*)(ws + 40 * MB);  //  8 MB [4096][1024]

    cvt_all<<<dim3(1024), dim3(256), 0, stream>>>(
        x, Wq, Wk, Wv, Wo, xb, Wqb, Wkb, Wvb, Wob);

    gemm_bt<0><<<dim3(32, 24), dim3(256), 0, stream>>>(
        xb, Wqb, Wkb, Wvb, bq, bk, bv, Qb, Kb, Vtb, nullptr);

    attn_kernel<<<dim3(16, 32), dim3(256), 0, stream>>>(Qb, Kb, Vtb, attnb);

    gemm_bt<1><<<dim3(64, 8), dim3(256), 0, stream>>>(
        attnb, Wob, nullptr, nullptr, bo, nullptr, nullptr,
        nullptr, nullptr, nullptr, (float*)d_out);
}

// Round 5
// 199.130 us; speedup vs baseline: 1.5576x; 1.0474x over previous
//
#include <hip/hip_runtime.h>
#include <stdint.h>

// ---------------------------------------------------------------------------
// MultiHeadAttention  B=2 S=2048 D=1024 H=16 HD=64   (fp32 in/out, bf16 MFMA)
// convert->bf16, fused QKV GEMM, flash attention (S^T form, x32 PV, s-split
// partials), partial-reduce, output GEMM.
// ---------------------------------------------------------------------------

typedef __bf16 bf16x8 __attribute__((ext_vector_type(8)));
typedef float  f32x4  __attribute__((ext_vector_type(4)));
typedef unsigned short u16x8 __attribute__((ext_vector_type(8)));

#define LOG2E 1.44269504088896f
#define FIXED_MAX_BITS 14.4269504088896f   /* 10 nats * log2(e) */

__device__ __forceinline__ unsigned short f2bf(float f) {
    union { float f; unsigned u; } v; v.f = f;
    unsigned r = v.u + 0x7FFFu + ((v.u >> 16) & 1u);   // round-to-nearest-even
    return (unsigned short)(r >> 16);
}
__device__ __forceinline__ float bf2f(unsigned short u) {
    union { unsigned u; float f; } v; v.u = (unsigned)u << 16; return v.f;
}

__device__ __forceinline__ float exp2_fast(float x) {
#if __has_builtin(__builtin_amdgcn_exp2f)
    return __builtin_amdgcn_exp2f(x);
#else
    return __expf(x * 0.69314718056f);
#endif
}

// async global->LDS, 16B per lane; lds dest = wave-uniform base + lane*16
__device__ __forceinline__ void glds16(const void* g, void* l) {
    __builtin_amdgcn_global_load_lds(
        (__attribute__((address_space(1))) void*)(g),
        (__attribute__((address_space(3))) void*)(l),
        16, 0, 0);
}

// ---------------------------------------------------------------------------
// fp32 -> bf16 convert: x (1M float4) + 4 weights (256K float4 each), 1 launch
// ---------------------------------------------------------------------------
__global__ __launch_bounds__(256) void cvt_all(
    const float* __restrict__ x,  const float* __restrict__ Wq,
    const float* __restrict__ Wk, const float* __restrict__ Wv,
    const float* __restrict__ Wo,
    unsigned short* __restrict__ xb,  unsigned short* __restrict__ Wqb,
    unsigned short* __restrict__ Wkb, unsigned short* __restrict__ Wvb,
    unsigned short* __restrict__ Wob)
{
    const int stride = gridDim.x * blockDim.x;
    for (int i = blockIdx.x * blockDim.x + threadIdx.x; i < 2097152; i += stride) {
        const float* src; unsigned short* dst; int j;
        if (i < 1048576) { src = x; dst = xb; j = i; }
        else {
            int t = (i - 1048576) >> 18; j = (i - 1048576) & 262143;
            src = (t == 0) ? Wq : (t == 1) ? Wk : (t == 2) ? Wv : Wo;
            dst = (t == 0) ? Wqb : (t == 1) ? Wkb : (t == 2) ? Wvb : Wob;
        }
        float4 v = ((const float4*)src)[j];
        ushort4 o;
        o.x = f2bf(v.x); o.y = f2bf(v.y); o.z = f2bf(v.z); o.w = f2bf(v.w);
        ((ushort4*)dst)[j] = o;
    }
}

// ---------------------------------------------------------------------------
// GEMM  C[m][n] = sum_k A[m][k] * W[n][k]  (+bias)   (unchanged from round 2)
// ---------------------------------------------------------------------------
template <int MODE>
__global__ __launch_bounds__(256) void gemm_bt(
    const unsigned short* __restrict__ A,
    const unsigned short* __restrict__ W0,
    const unsigned short* __restrict__ W1,
    const unsigned short* __restrict__ W2,
    const float* __restrict__ b0,
    const float* __restrict__ b1,
    const float* __restrict__ b2,
    unsigned short* __restrict__ outQ,
    unsigned short* __restrict__ outK,
    unsigned short* __restrict__ outV,
    float* __restrict__ outF)
{
    constexpr int BM = (MODE == 0) ? 128 : 64;
    constexpr int FM = BM / 32;
    constexpr int RA = BM / 32;

    __shared__ __attribute__((aligned(16))) unsigned short As[BM * 64];
    __shared__ __attribute__((aligned(16))) unsigned short Bs[128 * 64];

    const int tid  = threadIdx.x;
    const int lane = tid & 63;
    const int wid  = tid >> 6;
    const int quad = lane >> 4;
    const int l16  = lane & 15;

    const int m0 = blockIdx.x * BM;

    const unsigned short* W;
    const float* bias;
    int proj, n0;
    if (MODE == 0) {
        proj = blockIdx.y >> 3;
        n0   = (blockIdx.y & 7) * 128;
        W    = (proj == 0) ? W0 : (proj == 1) ? W1 : W2;
        bias = (proj == 0) ? b0 : (proj == 1) ? b1 : b2;
    } else {
        proj = 0;
        n0   = blockIdx.y * 128;
        W    = W0;
        bias = b0;
    }

    const int wm = (wid >> 1) * (BM / 2);
    const int wn = (wid & 1) * 64;

    f32x4 acc[FM][4];
#pragma unroll
    for (int i = 0; i < FM; ++i)
#pragma unroll
        for (int j = 0; j < 4; ++j)
            acc[i][j] = (f32x4){0.f, 0.f, 0.f, 0.f};

    char* AsB  = (char*)As;
    char* BsB  = (char*)Bs;
    char* ldsA = AsB + wid * 1024;
    char* ldsB = BsB + wid * 1024;

    for (int k0 = 0; k0 < 1024; k0 += 64) {
#pragma unroll
        for (int q = 0; q < RA; ++q) {
            int i   = q * 256 + tid;
            int row = i >> 3;
            int sc  = (i & 7) ^ (row & 7);
            glds16(A + (size_t)(m0 + row) * 1024 + k0 + sc * 8, ldsA + q * 4096);
        }
#pragma unroll
        for (int q = 0; q < 4; ++q) {
            int i   = q * 256 + tid;
            int row = i >> 3;
            int sc  = (i & 7) ^ (row & 7);
            glds16(W + (size_t)(n0 + row) * 1024 + k0 + sc * 8, ldsB + q * 4096);
        }
        __syncthreads();

#pragma unroll
        for (int kh = 0; kh < 2; ++kh) {
            bf16x8 af[FM], bfr[4];
#pragma unroll
            for (int t = 0; t < FM; ++t) {
                int r = wm + t * 16 + l16;
                int c = (kh * 4 + quad) ^ (r & 7);
                af[t] = *(const bf16x8*)(AsB + r * 128 + c * 16);
            }
#pragma unroll
            for (int t = 0; t < 4; ++t) {
                int r = wn + t * 16 + l16;
                int c = (kh * 4 + quad) ^ (r & 7);
                bfr[t] = *(const bf16x8*)(BsB + r * 128 + c * 16);
            }
#pragma unroll
            for (int i = 0; i < FM; ++i)
#pragma unroll
                for (int j = 0; j < 4; ++j)
                    acc[i][j] = __builtin_amdgcn_mfma_f32_16x16x32_bf16(
                        af[i], bfr[j], acc[i][j], 0, 0, 0);
        }
        __syncthreads();
    }

#pragma unroll
    for (int i = 0; i < FM; ++i) {
        const int mrow0 = m0 + wm + i * 16 + quad * 4;
#pragma unroll
        for (int j = 0; j < 4; ++j) {
            const int n  = n0 + wn + j * 16 + l16;
            const float bb = bias[n];
            if (MODE == 1) {
#pragma unroll
                for (int r = 0; r < 4; ++r)
                    outF[(size_t)(mrow0 + r) * 1024 + n] = acc[i][j][r] + bb;
            } else {
                const int h = n >> 6, hd = n & 63;
                if (proj == 2) {
                    const int b = mrow0 >> 11, s = mrow0 & 2047;
                    ushort4 pk;
                    pk.x = f2bf(acc[i][j][0] + bb);
                    pk.y = f2bf(acc[i][j][1] + bb);
                    pk.z = f2bf(acc[i][j][2] + bb);
                    pk.w = f2bf(acc[i][j][3] + bb);
                    *(ushort4*)(outV + ((size_t)((b * 16 + h) * 64 + hd)) * 2048 + s) = pk;
                } else {
                    unsigned short* dst = (proj == 0) ? outQ : outK;
                    const float scl = (proj == 0) ? (0.125f * LOG2E) : 1.0f;
#pragma unroll
                    for (int r = 0; r < 4; ++r) {
                        const int m = mrow0 + r;
                        const int b = m >> 11, s = m & 2047;
                        dst[((size_t)((b * 16 + h) * 2048 + s)) * 64 + hd] =
                            f2bf((acc[i][j][r] + bb) * scl);
                    }
                }
            }
        }
    }
}

// ---------------------------------------------------------------------------
// Flash attention, S^T form, x32 PV, s-split partials.
// Block = (qtile 128, s-half 1024, bh); 4 waves x 32 q.
// QK s->m remap: A-frag lane reads K row 32*st32 + 8*(l16>>2) + 4F + (l16&3),
// with Ks chunk swizzle g(s)=(s&3)|(((s>>3)&1)<<2) keeping reads conflict-free.
// Then C-frag(quad,reg r) holds s = 32*st32 + 8*quad + 4F + r, so frag pair
// (F=0,1) packs directly into the 16x16x32 PV B-operand (k = quad*8+j).
// V A-frag = one b128 per (ht,st32), conflict-free. Fixed-max softmax:
// p = exp2(acc), acc init = -10*log2e, log2e baked into Q. Partials (O, lsum)
// are additive across s-halves -> no rescaling, combined by attn_reduce.
// ---------------------------------------------------------------------------
__global__ __launch_bounds__(256, 4) void attn_kernel(
    const unsigned short* __restrict__ Qb,   // [32][2048][64]
    const unsigned short* __restrict__ Kb,   // [32][2048][64]
    const unsigned short* __restrict__ Vtb,  // [32][64][2048]
    unsigned short* __restrict__ OP,         // [2][4096][1024] bf16 partial O
    float* __restrict__ LS)                  // [2][32][2048] partial lsum
{
    __shared__ __attribute__((aligned(16))) unsigned short Ks[128 * 64];    // 16 KB
    __shared__ __attribute__((aligned(16))) unsigned short Vs[2 * 64 * 64]; // 16 KB

    const int tid  = threadIdx.x;
    const int lane = tid & 63;
    const int wid  = tid >> 6;
    const int quad = lane >> 4;
    const int l16  = lane & 15;
    const int l7   = l16 & 7;

    const int half = blockIdx.x & 1;
    const int q0   = (blockIdx.x >> 1) * 128 + wid * 32;
    const int hb   = blockIdx.y;              // b*16 + h
    const int bq   = hb >> 4, hh = hb & 15;

    const unsigned short* Qh  = Qb  + (size_t)hb * 2048 * 64;
    const unsigned short* Kh  = Kb  + (size_t)hb * 2048 * 64;
    const unsigned short* Vth = Vtb + (size_t)hb * 64 * 2048;

    // Q B-frags: B[k=d][n=q], lane n=l16, k=quad*8+j; kh = d-half
    bf16x8 qf[2][2];
#pragma unroll
    for (int qt = 0; qt < 2; ++qt) {
        const unsigned short* qp = Qh + (size_t)(q0 + qt * 16 + l16) * 64 + quad * 8;
        qf[qt][0] = *(const bf16x8*)(qp);
        qf[qt][1] = *(const bf16x8*)(qp + 32);
    }

    f32x4 o[4][2];   // O^T accumulators: [hd-tile][q-tile]
#pragma unroll
    for (int ht = 0; ht < 4; ++ht)
#pragma unroll
        for (int qt = 0; qt < 2; ++qt)
            o[ht][qt] = (f32x4){0.f, 0.f, 0.f, 0.f};
    float lsum[2] = {0.f, 0.f};

    char* KsB  = (char*)Ks;
    char* ldsK = KsB + wid * 1024;

    // lane-constant pieces of the fragment addresses
    const int base_row = 8 * (l16 >> 2) + (l16 & 3);   // K s->m remap, F=0
    const int kp0 = ((quad) ^ l7) * 16;                // d-half 0 chunk
    const int kp1 = ((4 + quad) ^ l7) * 16;            // d-half 1 chunk
    const int vrow = l16 * 128;

    const int kc0 = half * 1024;
    for (int kc = kc0; kc < kc0 + 1024; kc += 128) {
        // stage K 128x64 with g(s) swizzle (4 rounds of 4KB)
#pragma unroll
        for (int q = 0; q < 4; ++q) {
            int i   = q * 256 + tid;
            int row = i >> 3;
            int g   = (row & 3) | (((row >> 3) & 1) << 2);
            int ch  = (i & 7) ^ g;
            glds16(Kh + (size_t)(kc + row) * 64 + ch * 8, ldsK + q * 4096);
        }
        // stage Vt 2x 64x64 with (row&7) swizzle
#pragma unroll
        for (int sub = 0; sub < 2; ++sub)
#pragma unroll
            for (int q = 0; q < 2; ++q) {
                int i   = q * 256 + tid;
                int row = i >> 3;
                int ch  = (i & 7) ^ (row & 7);
                glds16(Vth + (size_t)row * 2048 + kc + sub * 64 + ch * 8,
                       (char*)Vs + sub * 8192 + wid * 1024 + q * 4096);
            }
        __syncthreads();

#pragma unroll
        for (int st32 = 0; st32 < 4; ++st32) {   // 32 s per step
            const char* krb = KsB + (st32 * 32 + base_row) * 128;
            bf16x8 kf00 = *(const bf16x8*)(krb + kp0);
            bf16x8 kf01 = *(const bf16x8*)(krb + kp1);
            bf16x8 kf10 = *(const bf16x8*)(krb + 512 + kp0);   // F=1: +4 rows
            bf16x8 kf11 = *(const bf16x8*)(krb + 512 + kp1);

            const f32x4 mi = (f32x4){-FIXED_MAX_BITS, -FIXED_MAX_BITS,
                                     -FIXED_MAX_BITS, -FIXED_MAX_BITS};
            f32x4 s00 = mi, s01 = mi, s10 = mi, s11 = mi;  // [qt][F]
            s00 = __builtin_amdgcn_mfma_f32_16x16x32_bf16(kf00, qf[0][0], s00, 0, 0, 0);
            s00 = __builtin_amdgcn_mfma_f32_16x16x32_bf16(kf01, qf[0][1], s00, 0, 0, 0);
            s01 = __builtin_amdgcn_mfma_f32_16x16x32_bf16(kf10, qf[0][0], s01, 0, 0, 0);
            s01 = __builtin_amdgcn_mfma_f32_16x16x32_bf16(kf11, qf[0][1], s01, 0, 0, 0);
            s10 = __builtin_amdgcn_mfma_f32_16x16x32_bf16(kf00, qf[1][0], s10, 0, 0, 0);
            s10 = __builtin_amdgcn_mfma_f32_16x16x32_bf16(kf01, qf[1][1], s10, 0, 0, 0);
            s11 = __builtin_amdgcn_mfma_f32_16x16x32_bf16(kf10, qf[1][0], s11, 0, 0, 0);
            s11 = __builtin_amdgcn_mfma_f32_16x16x32_bf16(kf11, qf[1][1], s11, 0, 0, 0);

            bf16x8 p8[2];
#pragma unroll
            for (int qt = 0; qt < 2; ++qt) {
                const f32x4 sA = qt ? s10 : s00;
                const f32x4 sB = qt ? s11 : s01;
                float e0 = exp2_fast(sA[0]), e1 = exp2_fast(sA[1]);
                float e2 = exp2_fast(sA[2]), e3 = exp2_fast(sA[3]);
                float e4 = exp2_fast(sB[0]), e5 = exp2_fast(sB[1]);
                float e6 = exp2_fast(sB[2]), e7 = exp2_fast(sB[3]);
                lsum[qt] += ((e0 + e1) + (e2 + e3)) + ((e4 + e5) + (e6 + e7));
                u16x8 up;
                up[0] = f2bf(e0); up[1] = f2bf(e1); up[2] = f2bf(e2); up[3] = f2bf(e3);
                up[4] = f2bf(e4); up[5] = f2bf(e5); up[6] = f2bf(e6); up[7] = f2bf(e7);
                p8[qt] = __builtin_bit_cast(bf16x8, up);
            }

            // V A-frags: one b128 per ht, chunk (st32&1)*4+quad (swizzled)
            const int voff = (st32 >> 1) * 8192 + vrow
                           + ((((st32 & 1) * 4 + quad) ^ l7) * 16);
#pragma unroll
            for (int ht = 0; ht < 4; ++ht) {
                const bf16x8 vf = *(const bf16x8*)((char*)Vs + voff + ht * 2048);
                o[ht][0] = __builtin_amdgcn_mfma_f32_16x16x32_bf16(vf, p8[0], o[ht][0], 0, 0, 0);
                o[ht][1] = __builtin_amdgcn_mfma_f32_16x16x32_bf16(vf, p8[1], o[ht][1], 0, 0, 0);
            }
        }
        __syncthreads();
    }

    // reduce lsum across quads (same l16 holds same q)
    float lt[2];
#pragma unroll
    for (int qt = 0; qt < 2; ++qt) {
        float s = lsum[qt];
        s += __shfl_xor(s, 16);
        s += __shfl_xor(s, 32);
        lt[qt] = s;
    }

    // write partial O (unnormalized) and partial lsum
    unsigned short* OPh = OP + (size_t)half * 4096 * 1024;
#pragma unroll
    for (int qt = 0; qt < 2; ++qt) {
        const size_t row = (size_t)(bq * 2048 + q0 + qt * 16 + l16);
#pragma unroll
        for (int ht = 0; ht < 4; ++ht) {
            ushort4 pk;
            pk.x = f2bf(o[ht][qt][0]);
            pk.y = f2bf(o[ht][qt][1]);
            pk.z = f2bf(o[ht][qt][2]);
            pk.w = f2bf(o[ht][qt][3]);
            *(ushort4*)(OPh + row * 1024 + hh * 64 + ht * 16 + quad * 4) = pk;
        }
    }
    if (quad == 0) {
        LS[half * 65536 + hb * 2048 + q0 + l16]      = lt[0];
        LS[half * 65536 + hb * 2048 + q0 + 16 + l16] = lt[1];
    }
}

// ---------------------------------------------------------------------------
// combine s-half partials: attnb = (OP0 + OP1) / (LS0 + LS1)
// ---------------------------------------------------------------------------
__global__ __launch_bounds__(256) void attn_reduce(
    const unsigned short* __restrict__ OP,   // [2][4096][1024]
    const float* __restrict__ LS,            // [2][32][2048]
    unsigned short* __restrict__ attnb)      // [4096][1024]
{
    const size_t idx = ((size_t)blockIdx.x * 256 + threadIdx.x) * 8;
    const int row = (int)(idx >> 10);
    const int col = (int)(idx & 1023);
    const int bh  = ((row >> 11) << 4) + (col >> 6);
    const int q   = row & 2047;
    const float l = LS[bh * 2048 + q] + LS[65536 + bh * 2048 + q];
    const float rl = 1.0f / l;

    ushort4 a0 = *(const ushort4*)(OP + idx);
    ushort4 a1 = *(const ushort4*)(OP + idx + 4);
    ushort4 b0 = *(const ushort4*)(OP + 4194304 + idx);
    ushort4 b1 = *(const ushort4*)(OP + 4194304 + idx + 4);
    ushort4 o0, o1;
    o0.x = f2bf((bf2f(a0.x) + bf2f(b0.x)) * rl);
    o0.y = f2bf((bf2f(a0.y) + bf2f(b0.y)) * rl);
    o0.z = f2bf((bf2f(a0.z) + bf2f(b0.z)) * rl);
    o0.w = f2bf((bf2f(a0.w) + bf2f(b0.w)) * rl);
    o1.x = f2bf((bf2f(a1.x) + bf2f(b1.x)) * rl);
    o1.y = f2bf((bf2f(a1.y) + bf2f(b1.y)) * rl);
    o1.z = f2bf((bf2f(a1.z) + bf2f(b1.z)) * rl);
    o1.w = f2bf((bf2f(a1.w) + bf2f(b1.w)) * rl);
    *(ushort4*)(attnb + idx)     = o0;
    *(ushort4*)(attnb + idx + 4) = o1;
}

// ---------------------------------------------------------------------------
// launch
// ---------------------------------------------------------------------------
extern "C" void kernel_launch(void* const* d_in, const int* in_sizes, int n_in,
                              void* d_out, int out_size, void* d_ws, size_t ws_size,
                              hipStream_t stream) {
    (void)in_sizes; (void)n_in; (void)out_size; (void)ws_size;

    const float* x  = (const float*)d_in[0];
    const float* Wq = (const float*)d_in[1];
    const float* bq = (const float*)d_in[2];
    const float* Wk = (const float*)d_in[3];
    const float* bk = (const float*)d_in[4];
    const float* Wv = (const float*)d_in[5];
    const float* bv = (const float*)d_in[6];
    const float* Wo = (const float*)d_in[7];
    const float* bo = (const float*)d_in[8];

    char* ws = (char*)d_ws;
    const size_t MB = 1024 * 1024;
    unsigned short* xb    = (unsigned short*)(ws + 0);        //  8 MB [4096][1024]
    unsigned short* Wqb   = (unsigned short*)(ws + 8  * MB);  //  2 MB
    unsigned short* Wkb   = (unsigned short*)(ws + 10 * MB);
    unsigned short* Wvb   = (unsigned short*)(ws + 12 * MB);
    unsigned short* Wob   = (unsigned short*)(ws + 14 * MB);
    unsigned short* Qb    = (unsigned short*)(ws + 16 * MB);  //  8 MB [32][2048][64]
    unsigned short* Kb    = (unsigned short*)(ws + 24 * MB);  //  8 MB
    unsigned short* Vtb   = (unsigned short*)(ws + 32 * MB);  //  8 MB [32][64][2048]
    unsigned short* attnb = (unsigned short*)(ws + 40 * MB);  //  8 MB [4096][1024]
    unsigned short* OP    = (unsigned short*)(ws + 48 * MB);  // 16 MB [2][4096][1024]
    float*          LSb   = (float*)(ws + 64 * MB);           // 512 KB [2][32][2048]

    cvt_all<<<dim3(1024), dim3(256), 0, stream>>>(
        x, Wq, Wk, Wv, Wo, xb, Wqb, Wkb, Wvb, Wob);

    gemm_bt<0><<<dim3(32, 24), dim3(256), 0, stream>>>(
        xb, Wqb, Wkb, Wvb, bq, bk, bv, Qb, Kb, Vtb, nullptr);

    attn_kernel<<<dim3(32, 32), dim3(256), 0, stream>>>(Qb, Kb, Vtb, OP, LSb);

    attn_reduce<<<dim3(2048), dim3(256), 0, stream>>>(OP, LSb, attnb);

    gemm_bt<1><<<dim3(64, 8), dim3(256), 0, stream>>>(
        attnb, Wob, nullptr, nullptr, bo, nullptr, nullptr,
        nullptr, nullptr, nullptr, (float*)d_out);
}